// Round 1
// baseline (498.272 us; speedup 1.0000x reference)
//
#include <hip/hip_runtime.h>
#include <hip/hip_bf16.h>

// FixedChannelDP: y[p, n] = sum_{k=0}^{L-1} h[k] * x[p, n-k]  ('full' conv)
// x complex from (tx_real, tx_imag), h complex from (h_real, h_imag).
// Output float32 [2, NOUT, 2] with real/imag interleaved in last dim.

#define NSAMP 4194304
#define LTAPS 513
#define NOUT  (NSAMP + LTAPS - 1)   // 4194816

#define BLK   256
#define RPT   9                     // outputs per thread; 513 % 9 == 0, odd stride -> no LDS bank conflicts
#define TILE  (BLK * RPT)           // 2304 outputs per block
#define HALO  (LTAPS - 1)           // 512
#define XLEN  (TILE + HALO)         // 2816 staged x samples
#define NBLK  ((NOUT + TILE - 1) / TILE)  // 1821

__global__ __launch_bounds__(BLK)
void fir_full_f32(const float* __restrict__ txr_all,
                  const float* __restrict__ txi_all,
                  const float* __restrict__ hr,
                  const float* __restrict__ hi,
                  float2* __restrict__ out) {
    const int pol = blockIdx.y;
    const int n0  = blockIdx.x * TILE;
    const int tid = threadIdx.x;

    const float* __restrict__ txr = txr_all + (size_t)pol * NSAMP;
    const float* __restrict__ txi = txi_all + (size_t)pol * NSAMP;

    // +1 front pad: the final (unused) window refill at k=L-1 reads index -1.
    __shared__ float xr_s[XLEN + 1];
    __shared__ float xi_s[XLEN + 1];

    // Stage x tile [n0-HALO, n0+TILE) with zero padding outside [0, NSAMP).
    const int g0 = n0 - HALO;
    #pragma unroll
    for (int s = 0; s < XLEN / BLK; ++s) {  // 2816/256 = 11
        int idx = tid + BLK * s;
        int g   = g0 + idx;
        int gc  = min(max(g, 0), NSAMP - 1);
        float vr = txr[gc];
        float vi = txi[gc];
        bool ok = (g >= 0) && (g < NSAMP);
        xr_s[idx + 1] = ok ? vr : 0.0f;
        xi_s[idx + 1] = ok ? vi : 0.0f;
    }
    __syncthreads();

    // Register sliding window: slot s holds x[p0 - k + j], j = (s + k) % RPT.
    // (mapping s = (j - k) mod RPT: values never move; one slot refilled per tap)
    const int p0 = tid * RPT + HALO;  // LDS-local coord (before +1 pad shift)

    float wr[RPT], wi[RPT], ar[RPT], ai[RPT];
    #pragma unroll
    for (int j = 0; j < RPT; ++j) {
        wr[j] = xr_s[p0 + j + 1];
        wi[j] = xi_s[p0 + j + 1];
        ar[j] = 0.0f;
        ai[j] = 0.0f;
    }

    for (int kb = 0; kb < LTAPS; kb += RPT) {   // 57 iterations
        #pragma unroll
        for (int kk = 0; kk < RPT; ++kk) {
            const int k = kb + kk;
            const float hrk = hr[k];   // uniform -> scalar load
            const float hik = hi[k];
            #pragma unroll
            for (int r = 0; r < RPT; ++r) {
                int s = r - kk; if (s < 0) s += RPT;   // compile-time constant
                ar[r] = fmaf(hrk, wr[s], ar[r]);
                ar[r] = fmaf(-hik, wi[s], ar[r]);
                ai[r] = fmaf(hrk, wi[s], ai[r]);
                ai[r] = fmaf(hik, wr[s], ai[r]);
            }
            // Refill the slot just freed (j = 0 for tap k+1): slot (8 - kk),
            // value x[p0 - (k+1)] -> LDS index (p0 - k - 1) + 1 = p0 - k.
            const int snew = (RPT - 1) - kk;
            wr[snew] = xr_s[p0 - k];
            wi[snew] = xi_s[p0 - k];
        }
    }

    // Store: out[pol][n] = (ar, ai) as float2 (matches [2, NOUT, 2] layout).
    float2* __restrict__ op = out + (size_t)pol * NOUT;
    const int nbase = n0 + tid * RPT;
    #pragma unroll
    for (int r = 0; r < RPT; ++r) {
        int n = nbase + r;
        if (n < NOUT) op[n] = make_float2(ar[r], ai[r]);
    }
}

extern "C" void kernel_launch(void* const* d_in, const int* in_sizes, int n_in,
                              void* d_out, int out_size, void* d_ws, size_t ws_size,
                              hipStream_t stream) {
    const float* txr = (const float*)d_in[0];
    const float* txi = (const float*)d_in[1];
    const float* hr  = (const float*)d_in[2];
    const float* hi  = (const float*)d_in[3];
    float2* out = (float2*)d_out;

    dim3 grid(NBLK, 2);
    fir_full_f32<<<grid, BLK, 0, stream>>>(txr, txi, hr, hi, out);
}

// Round 2
// 165.792 us; speedup vs baseline: 3.0054x; 3.0054x over previous
//
#include <hip/hip_runtime.h>
#include <hip/hip_bf16.h>

// FixedChannelDP via Toeplitz-GEMM on bf16 MFMA.
// y[p,n] = sum_{k=0}^{512} h[k] x[p,n-k]  ('full' conv), out fp32 [2,NOUT,2].
//
// MFMA mapping (16x16x32 bf16, verified A/B/C layouts per m89):
//   call b in [0,17):  D[r][c] += sum_k A_b[r][k]*B_b[k][c]
//   A_b[r][k] = x[n0 + 16r + k - 32b]   (lane: 8 contiguous x -> ds_read_b128)
//   B_b[k][c] = h[32b + c - k] (0 if OOB) -> tap t = 32b+c-k covers [0,512] exactly once.

#define NSAMP 4194304
#define LTAPS 513
#define NOUT  (NSAMP + LTAPS - 1)   // 4194816

#define BLK       256
#define WAVES     4
#define MR        8                   // 16x16 tiles per wave
#define TILE_OUT  256
#define WAVE_OUT  (MR * TILE_OUT)     // 2048
#define BLOCK_OUT (WAVES * WAVE_OUT)  // 8192
#define HALO      512
#define XELEMS    (BLOCK_OUT + HALO + 16)  // 8720 (A-frags read 16 past tile end at b=0)
#define NB        17

// x LDS swizzle: +8 elements (16 B) pad per 64 elements -> A-frag reads <=2-way banked
__device__ __forceinline__ int xswz(int e) { return e + ((e >> 6) << 3); }
#define XSZ 9808   // xswz(8719)=9807, +1 for b128 tail

// hA8 table: row R in [0,552), hA8[R][t] = h[R - 24 - t] (0 if OOB).
// Row start (short index) = 8R + 8*(R>>3): 16 B rows + 16 B pad per 8 rows.
#define HROWS 552
__device__ __forceinline__ int hswz(int R) { return (R << 3) + ((R >> 3) << 3); }
#define HSZ 4968

typedef __attribute__((ext_vector_type(8))) short short8;
typedef __attribute__((ext_vector_type(4))) short short4v;
typedef __attribute__((ext_vector_type(4))) float float4v;

__device__ __forceinline__ short f2b(float f) {
    __bf16 b = (__bf16)f;
    return __builtin_bit_cast(short, b);
}

__global__ __launch_bounds__(BLK, 2)
void fir_mfma(const float* __restrict__ txr_all, const float* __restrict__ txi_all,
              const float* __restrict__ hr_g, const float* __restrict__ hi_g,
              float2* __restrict__ out) {
    const int pol = blockIdx.y;
    const long long N0 = (long long)blockIdx.x * BLOCK_OUT;
    const int tid = threadIdx.x;

    __shared__ short xr_s[XSZ];
    __shared__ short xi_s[XSZ];
    __shared__ short hr_s[HSZ];
    __shared__ short hi_s[HSZ];
    __shared__ short nhi_s[HSZ];

    const float* __restrict__ xr_g = txr_all + (size_t)pol * NSAMP;
    const float* __restrict__ xi_g = txi_all + (size_t)pol * NSAMP;

    // ---- stage x tile [N0-HALO, N0+BLOCK_OUT+16) as bf16, swizzled ----
    #pragma unroll
    for (int it = 0; it < 9; ++it) {
        int e = (tid + it * BLK) * 4;
        if (e < XELEMS) {
            long long g = N0 - HALO + e;
            float r0, r1, r2, r3, i0, i1, i2, i3;
            if (g >= 0 && g + 3 < NSAMP) {
                float4 fr = *(const float4*)(xr_g + g);
                float4 fi = *(const float4*)(xi_g + g);
                r0 = fr.x; r1 = fr.y; r2 = fr.z; r3 = fr.w;
                i0 = fi.x; i1 = fi.y; i2 = fi.z; i3 = fi.w;
            } else {
                long long gc0 = min(max(g + 0, 0LL), (long long)NSAMP - 1);
                long long gc1 = min(max(g + 1, 0LL), (long long)NSAMP - 1);
                long long gc2 = min(max(g + 2, 0LL), (long long)NSAMP - 1);
                long long gc3 = min(max(g + 3, 0LL), (long long)NSAMP - 1);
                r0 = (g + 0 >= 0 && g + 0 < NSAMP) ? xr_g[gc0] : 0.0f;
                r1 = (g + 1 >= 0 && g + 1 < NSAMP) ? xr_g[gc1] : 0.0f;
                r2 = (g + 2 >= 0 && g + 2 < NSAMP) ? xr_g[gc2] : 0.0f;
                r3 = (g + 3 >= 0 && g + 3 < NSAMP) ? xr_g[gc3] : 0.0f;
                i0 = (g + 0 >= 0 && g + 0 < NSAMP) ? xi_g[gc0] : 0.0f;
                i1 = (g + 1 >= 0 && g + 1 < NSAMP) ? xi_g[gc1] : 0.0f;
                i2 = (g + 2 >= 0 && g + 2 < NSAMP) ? xi_g[gc2] : 0.0f;
                i3 = (g + 3 >= 0 && g + 3 < NSAMP) ? xi_g[gc3] : 0.0f;
            }
            int ls = xswz(e);   // e % 4 == 0 -> same 64-group for all 4
            short4v vr = { f2b(r0), f2b(r1), f2b(r2), f2b(r3) };
            short4v vi = { f2b(i0), f2b(i1), f2b(i2), f2b(i3) };
            *(short4v*)(xr_s + ls) = vr;
            *(short4v*)(xi_s + ls) = vi;
        }
    }

    // ---- build hA8 tables (hr, hi, -hi) ----
    #pragma unroll
    for (int it = 0; it < 3; ++it) {
        int R = tid + it * BLK;
        if (R < HROWS) {
            short8 vr, vi, vni;
            #pragma unroll
            for (int t = 0; t < 8; ++t) {
                int idx = R - 24 - t;
                float fr = (idx >= 0 && idx < LTAPS) ? hr_g[idx] : 0.0f;
                float fi = (idx >= 0 && idx < LTAPS) ? hi_g[idx] : 0.0f;
                vr[t] = f2b(fr);
                vi[t] = f2b(fi);
                vni[t] = f2b(-fi);
            }
            int hs = hswz(R);
            *(short8*)(hr_s + hs) = vr;
            *(short8*)(hi_s + hs) = vi;
            *(short8*)(nhi_s + hs) = vni;
        }
    }

    __syncthreads();

    // ---- MFMA main loop ----
    const int lane = tid & 63;
    const int wave = tid >> 6;
    const int c = lane & 15;   // A row / B col / D col
    const int q = lane >> 4;   // k-quad

    float4v acc_re[MR], acc_im[MR];
    #pragma unroll
    for (int m = 0; m < MR; ++m) {
        acc_re[m] = (float4v){0.f, 0.f, 0.f, 0.f};
        acc_im[m] = (float4v){0.f, 0.f, 0.f, 0.f};
    }

    for (int b = 0; b < NB; ++b) {
        int Rh = 32 * b + c - 8 * q + 24;           // [0, 551]
        int hs = hswz(Rh);
        short8 fhr  = *(const short8*)(hr_s + hs);
        short8 fhi  = *(const short8*)(hi_s + hs);
        short8 fnhi = *(const short8*)(nhi_s + hs);
        int ebase = HALO + wave * WAVE_OUT + 16 * c + 8 * q - 32 * b;
        #pragma unroll
        for (int m = 0; m < MR; ++m) {
            int ls = xswz(ebase + m * TILE_OUT);
            short8 fxr = *(const short8*)(xr_s + ls);
            short8 fxi = *(const short8*)(xi_s + ls);
            acc_re[m] = __builtin_amdgcn_mfma_f32_16x16x32_bf16(fxr, fhr,  acc_re[m], 0, 0, 0);
            acc_re[m] = __builtin_amdgcn_mfma_f32_16x16x32_bf16(fxi, fnhi, acc_re[m], 0, 0, 0);
            acc_im[m] = __builtin_amdgcn_mfma_f32_16x16x32_bf16(fxr, fhi,  acc_im[m], 0, 0, 0);
            acc_im[m] = __builtin_amdgcn_mfma_f32_16x16x32_bf16(fxi, fhr,  acc_im[m], 0, 0, 0);
        }
    }

    // ---- epilogue: D col = lane&15, row = (lane>>4)*4 + reg ----
    float2* __restrict__ op = out + (size_t)pol * NOUT;
    const long long nwave = N0 + (long long)wave * WAVE_OUT;
    #pragma unroll
    for (int m = 0; m < MR; ++m) {
        #pragma unroll
        for (int v = 0; v < 4; ++v) {
            int rrow = q * 4 + v;
            long long n = nwave + m * TILE_OUT + 16 * rrow + c;
            if (n < NOUT) op[n] = make_float2(acc_re[m][v], acc_im[m][v]);
        }
    }
}

extern "C" void kernel_launch(void* const* d_in, const int* in_sizes, int n_in,
                              void* d_out, int out_size, void* d_ws, size_t ws_size,
                              hipStream_t stream) {
    const float* txr = (const float*)d_in[0];
    const float* txi = (const float*)d_in[1];
    const float* hr  = (const float*)d_in[2];
    const float* hi  = (const float*)d_in[3];
    float2* out = (float2*)d_out;

    const int blocks_per_pol = (NOUT + BLOCK_OUT - 1) / BLOCK_OUT;  // 513
    dim3 grid(blocks_per_pol, 2);
    fir_mfma<<<grid, BLK, 0, stream>>>(txr, txi, hr, hi, out);
}

// Round 3
// 147.158 us; speedup vs baseline: 3.3860x; 1.1266x over previous
//
#include <hip/hip_runtime.h>
#include <hip/hip_bf16.h>

// FixedChannelDP via Toeplitz-GEMM on bf16 MFMA 32x32x16.
// y[p,n] = sum_{k=0}^{512} h[k] x[p,n-k]  ('full' conv), out fp32 [2,NOUT,2].
//
// Mapping (b in [0,34)):
//   D[r][c] += sum_k A_b[r][k] * B_b[k][c],  n = nw + 32r + c
//   A_b[r][k] = x[nw + 32r + k + 16 - 16b]        (8 contiguous -> ds_read_b128)
//   B_b[k][c] = h[16b + c - k - 16]  (0 if OOB)   -> tap covered exactly once
// h table (global ws, built by pre-kernel): hh[tab][R][j] = h[R-24-j],
//   row read at R = 16b + c - 8*half + 8  (tab: 0=hr, 1=hi, 2=-hi)

#define NSAMP 4194304
#define LTAPS 513
#define NOUT  (NSAMP + LTAPS - 1)   // 4194816

#define BLK       256
#define WAVES     4
#define WAVE_OUT  1024                  // one 32x32 D tile per wave
#define BLOCK_OUT 4096
#define HALO      512
#define XELEMS    (BLOCK_OUT + HALO + 16)   // 4624
#define NB        34
#define HROWS     568
#define NBLK      ((NOUT + BLOCK_OUT - 1) / BLOCK_OUT)  // 1025

typedef __attribute__((ext_vector_type(8)))  short short8;
typedef __attribute__((ext_vector_type(4)))  short short4v;
typedef __attribute__((ext_vector_type(16))) float float16v;

// x LDS swizzle: +8 elements (16 B) per 32 elements -> lane-m stride 80 B,
// 8-lane service groups tile all 32 banks. Reads/writes never cross a pad
// (all fragment e's are 0 mod 8; pads at 32-boundaries).
__device__ __forceinline__ int xswz(int e) { return e + ((e >> 5) << 3); }
#define XSZ 5776   // xswz(4620)+4

__device__ __forceinline__ short f2b(float f) {
    __bf16 b = (__bf16)f;
    return __builtin_bit_cast(short, b);
}

__global__ __launch_bounds__(BLK)
void build_h(const float* __restrict__ hr, const float* __restrict__ hi,
             short* __restrict__ hh) {
    int R = blockIdx.x * BLK + threadIdx.x;
    if (R < HROWS) {
        short8 vr, vi, vn;
        #pragma unroll
        for (int j = 0; j < 8; ++j) {
            int idx = R - 24 - j;
            bool ok = (idx >= 0) && (idx < LTAPS);
            float fr = ok ? hr[idx] : 0.0f;
            float fi = ok ? hi[idx] : 0.0f;
            vr[j] = f2b(fr);
            vi[j] = f2b(fi);
            vn[j] = f2b(-fi);
        }
        *(short8*)(hh + (size_t)(0 * HROWS + R) * 8) = vr;
        *(short8*)(hh + (size_t)(1 * HROWS + R) * 8) = vi;
        *(short8*)(hh + (size_t)(2 * HROWS + R) * 8) = vn;
    }
}

__global__ __launch_bounds__(BLK, 4)
void fir_mfma32(const float* __restrict__ txr_all, const float* __restrict__ txi_all,
                const short* __restrict__ hh, float2* __restrict__ out) {
    const int pol = blockIdx.y;
    const int N0  = blockIdx.x * BLOCK_OUT;
    const int tid = threadIdx.x;

    __shared__ short xr_s[XSZ];
    __shared__ short xi_s[XSZ];

    const float* __restrict__ xr_g = txr_all + (size_t)pol * NSAMP;
    const float* __restrict__ xi_g = txi_all + (size_t)pol * NSAMP;

    // ---- stage x tile [N0-HALO, N0+BLOCK_OUT+16) as bf16, swizzled ----
    #pragma unroll
    for (int it = 0; it < 5; ++it) {
        int e = (tid + it * BLK) * 4;
        if (e < XELEMS) {
            int g = N0 - HALO + e;   // may be negative or >= NSAMP at edges
            float r0, r1, r2, r3, i0, i1, i2, i3;
            if (g >= 0 && g + 3 < NSAMP) {
                float4 fr = *(const float4*)(xr_g + g);
                float4 fi = *(const float4*)(xi_g + g);
                r0 = fr.x; r1 = fr.y; r2 = fr.z; r3 = fr.w;
                i0 = fi.x; i1 = fi.y; i2 = fi.z; i3 = fi.w;
            } else {
                int gc0 = min(max(g + 0, 0), NSAMP - 1);
                int gc1 = min(max(g + 1, 0), NSAMP - 1);
                int gc2 = min(max(g + 2, 0), NSAMP - 1);
                int gc3 = min(max(g + 3, 0), NSAMP - 1);
                r0 = (g + 0 >= 0 && g + 0 < NSAMP) ? xr_g[gc0] : 0.0f;
                r1 = (g + 1 >= 0 && g + 1 < NSAMP) ? xr_g[gc1] : 0.0f;
                r2 = (g + 2 >= 0 && g + 2 < NSAMP) ? xr_g[gc2] : 0.0f;
                r3 = (g + 3 >= 0 && g + 3 < NSAMP) ? xr_g[gc3] : 0.0f;
                i0 = (g + 0 >= 0 && g + 0 < NSAMP) ? xi_g[gc0] : 0.0f;
                i1 = (g + 1 >= 0 && g + 1 < NSAMP) ? xi_g[gc1] : 0.0f;
                i2 = (g + 2 >= 0 && g + 2 < NSAMP) ? xi_g[gc2] : 0.0f;
                i3 = (g + 3 >= 0 && g + 3 < NSAMP) ? xi_g[gc3] : 0.0f;
            }
            int ls = xswz(e);   // e % 4 == 0, never crosses a pad boundary
            short4v vr = { f2b(r0), f2b(r1), f2b(r2), f2b(r3) };
            short4v vi = { f2b(i0), f2b(i1), f2b(i2), f2b(i3) };
            *(short4v*)(xr_s + ls) = vr;
            *(short4v*)(xi_s + ls) = vi;
        }
    }
    __syncthreads();

    // ---- MFMA main loop ----
    const int lane = tid & 63;
    const int wave = tid >> 6;
    const int cc   = lane & 31;   // A row r / B col c / D col
    const int half = lane >> 5;

    float16v acc_re = {0.f,0.f,0.f,0.f,0.f,0.f,0.f,0.f,0.f,0.f,0.f,0.f,0.f,0.f,0.f,0.f};
    float16v acc_im = {0.f,0.f,0.f,0.f,0.f,0.f,0.f,0.f,0.f,0.f,0.f,0.f,0.f,0.f,0.f,0.f};

    const int   ebase = HALO + wave * WAVE_OUT + 32 * cc + 8 * half + 16;
    const short* hp0  = hh + (size_t)(cc - 8 * half + 8) * 8;

    for (int b = 0; b < NB; ++b) {
        const short* hp = hp0 + (size_t)(16 * b) * 8;
        short8 fhr = *(const short8*)(hp);
        short8 fhi = *(const short8*)(hp + (size_t)HROWS * 8);
        short8 fnh = *(const short8*)(hp + (size_t)(2 * HROWS) * 8);
        int ls = xswz(ebase - 16 * b);
        short8 fxr = *(const short8*)(xr_s + ls);
        short8 fxi = *(const short8*)(xi_s + ls);
        acc_re = __builtin_amdgcn_mfma_f32_32x32x16_bf16(fxr, fhr, acc_re, 0, 0, 0);
        acc_re = __builtin_amdgcn_mfma_f32_32x32x16_bf16(fxi, fnh, acc_re, 0, 0, 0);
        acc_im = __builtin_amdgcn_mfma_f32_32x32x16_bf16(fxr, fhi, acc_im, 0, 0, 0);
        acc_im = __builtin_amdgcn_mfma_f32_32x32x16_bf16(fxi, fhr, acc_im, 0, 0, 0);
    }

    // ---- epilogue: D col = lane&31, row = (reg&3) + 8*(reg>>2) + 4*half ----
    float2* __restrict__ op = out + (size_t)pol * NOUT;
    const int nw = N0 + wave * WAVE_OUT;
    #pragma unroll
    for (int v = 0; v < 16; ++v) {
        int row = (v & 3) + 8 * (v >> 2) + 4 * half;
        int n = nw + 32 * row + cc;
        if (n < NOUT) op[n] = make_float2(acc_re[v], acc_im[v]);
    }
}

extern "C" void kernel_launch(void* const* d_in, const int* in_sizes, int n_in,
                              void* d_out, int out_size, void* d_ws, size_t ws_size,
                              hipStream_t stream) {
    const float* txr = (const float*)d_in[0];
    const float* txi = (const float*)d_in[1];
    const float* hr  = (const float*)d_in[2];
    const float* hi  = (const float*)d_in[3];
    float2* out = (float2*)d_out;
    short* hh = (short*)d_ws;   // 3 * 568 * 8 bf16 = 27 KB

    build_h<<<dim3((HROWS + BLK - 1) / BLK), BLK, 0, stream>>>(hr, hi, hh);

    dim3 grid(NBLK, 2);
    fir_mfma32<<<grid, BLK, 0, stream>>>(txr, txi, hh, out);
}

// Round 4
// 146.508 us; speedup vs baseline: 3.4010x; 1.0044x over previous
//
#include <hip/hip_runtime.h>
#include <hip/hip_bf16.h>

// FixedChannelDP via Toeplitz-GEMM on bf16 MFMA 32x32x16, both pols per block.
// y[p,n] = sum_{k=0}^{512} h[k] x[p,n-k]  ('full' conv), out fp32 [2,NOUT,2].
//
// Mapping (b in [0,34)):
//   D[r][c] += sum_k A_b[r][k] * B_b[k][c],  n = nw + 32r + c
//   A_b[r][k] = x[nw + 32r + k + 16 - 16b]        (8 contiguous -> ds_read_b128)
//   B_b[k][c] = h[16b + c - k - 16]  (0 if OOB)   -> tap covered exactly once
// h table (global ws, built by pre-kernel): hh[tab][R][j] = h[R-24-j],
//   row read at R = 16b + cc - 8*half + 8  (tab: 0=hr, 1=hi, 2=-hi)

#define NSAMP 4194304
#define LTAPS 513
#define NOUT  (NSAMP + LTAPS - 1)   // 4194816

#define BLK       256
#define WAVE_OUT  1024                  // one 32x32 D tile per wave per pol
#define BLOCK_OUT 4096
#define HALO      512
#define XELEMS    (BLOCK_OUT + HALO + 16)   // 4624
#define NB        34
#define HROWS     568
#define NBLK      ((NOUT + BLOCK_OUT - 1) / BLOCK_OUT)  // 1025

typedef __attribute__((ext_vector_type(8)))  short short8;
typedef __attribute__((ext_vector_type(4)))  short short4v;
typedef __attribute__((ext_vector_type(16))) float float16v;

// x LDS swizzle: +8 elements (16 B) per 32 -> A-frag b128 reads hit all 32 banks once.
__device__ __forceinline__ int xswz(int e) { return e + ((e >> 5) << 3); }
#define XSZ 5776

__device__ __forceinline__ short f2b(float f) {
    __bf16 b = (__bf16)f;
    return __builtin_bit_cast(short, b);
}

__global__ __launch_bounds__(BLK)
void build_h(const float* __restrict__ hr, const float* __restrict__ hi,
             short* __restrict__ hh) {
    int R = blockIdx.x * BLK + threadIdx.x;
    if (R < HROWS) {
        short8 vr, vi, vn;
        #pragma unroll
        for (int j = 0; j < 8; ++j) {
            int idx = R - 24 - j;
            bool ok = (idx >= 0) && (idx < LTAPS);
            float fr = ok ? hr[idx] : 0.0f;
            float fi = ok ? hi[idx] : 0.0f;
            vr[j] = f2b(fr);
            vi[j] = f2b(fi);
            vn[j] = f2b(-fi);
        }
        *(short8*)(hh + (size_t)(0 * HROWS + R) * 8) = vr;
        *(short8*)(hh + (size_t)(1 * HROWS + R) * 8) = vi;
        *(short8*)(hh + (size_t)(2 * HROWS + R) * 8) = vn;
    }
}

#define MFMA32(A, B, C) __builtin_amdgcn_mfma_f32_32x32x16_bf16((A), (B), (C), 0, 0, 0)

__global__ __launch_bounds__(BLK, 3)
void fir_mfma32dp(const float* __restrict__ txr_all, const float* __restrict__ txi_all,
                  const short* __restrict__ hh, float2* __restrict__ out) {
    const int N0  = blockIdx.x * BLOCK_OUT;
    const int tid = threadIdx.x;

    __shared__ short xr_s[2][XSZ];
    __shared__ short xi_s[2][XSZ];

    // ---- stage x tiles (both pols) [N0-HALO, N0+BLOCK_OUT+16) as bf16, swizzled ----
    #pragma unroll
    for (int p = 0; p < 2; ++p) {
        const float* __restrict__ xr_g = txr_all + (size_t)p * NSAMP;
        const float* __restrict__ xi_g = txi_all + (size_t)p * NSAMP;
        #pragma unroll
        for (int it = 0; it < 5; ++it) {
            int e = (tid + it * BLK) * 4;
            if (e < XELEMS) {
                int g = N0 - HALO + e;
                float r0, r1, r2, r3, i0, i1, i2, i3;
                if (g >= 0 && g + 3 < NSAMP) {
                    float4 fr = *(const float4*)(xr_g + g);
                    float4 fi = *(const float4*)(xi_g + g);
                    r0 = fr.x; r1 = fr.y; r2 = fr.z; r3 = fr.w;
                    i0 = fi.x; i1 = fi.y; i2 = fi.z; i3 = fi.w;
                } else {
                    int gc0 = min(max(g + 0, 0), NSAMP - 1);
                    int gc1 = min(max(g + 1, 0), NSAMP - 1);
                    int gc2 = min(max(g + 2, 0), NSAMP - 1);
                    int gc3 = min(max(g + 3, 0), NSAMP - 1);
                    r0 = (g + 0 >= 0 && g + 0 < NSAMP) ? xr_g[gc0] : 0.0f;
                    r1 = (g + 1 >= 0 && g + 1 < NSAMP) ? xr_g[gc1] : 0.0f;
                    r2 = (g + 2 >= 0 && g + 2 < NSAMP) ? xr_g[gc2] : 0.0f;
                    r3 = (g + 3 >= 0 && g + 3 < NSAMP) ? xr_g[gc3] : 0.0f;
                    i0 = (g + 0 >= 0 && g + 0 < NSAMP) ? xi_g[gc0] : 0.0f;
                    i1 = (g + 1 >= 0 && g + 1 < NSAMP) ? xi_g[gc1] : 0.0f;
                    i2 = (g + 2 >= 0 && g + 2 < NSAMP) ? xi_g[gc2] : 0.0f;
                    i3 = (g + 3 >= 0 && g + 3 < NSAMP) ? xi_g[gc3] : 0.0f;
                }
                int ls = xswz(e);   // 4-aligned, never crosses a pad boundary
                short4v vr = { f2b(r0), f2b(r1), f2b(r2), f2b(r3) };
                short4v vi = { f2b(i0), f2b(i1), f2b(i2), f2b(i3) };
                *(short4v*)(&xr_s[p][ls]) = vr;
                *(short4v*)(&xi_s[p][ls]) = vi;
            }
        }
    }
    __syncthreads();

    // ---- MFMA main loop, 1-deep software pipeline ----
    const int lane = tid & 63;
    const int wave = tid >> 6;
    const int cc   = lane & 31;   // A row r / B col c / D col
    const int half = lane >> 5;

    float16v accr0 = {0.f,0.f,0.f,0.f,0.f,0.f,0.f,0.f,0.f,0.f,0.f,0.f,0.f,0.f,0.f,0.f};
    float16v acci0 = accr0, accr1 = accr0, acci1 = accr0;

    const int    ebase = HALO + wave * WAVE_OUT + 32 * cc + 8 * half + 16;
    const short* hp0   = hh + (size_t)(cc - 8 * half + 8) * 8;

    // prefetch b = 0
    short8 fhr  = *(const short8*)(hp0);
    short8 fhi  = *(const short8*)(hp0 + (size_t)HROWS * 8);
    short8 fnh  = *(const short8*)(hp0 + (size_t)(2 * HROWS) * 8);
    int ls0 = xswz(ebase);
    short8 fxr0 = *(const short8*)(&xr_s[0][ls0]);
    short8 fxi0 = *(const short8*)(&xi_s[0][ls0]);
    short8 fxr1 = *(const short8*)(&xr_s[1][ls0]);
    short8 fxi1 = *(const short8*)(&xi_s[1][ls0]);

    #pragma unroll 2
    for (int b = 0; b < NB; ++b) {
        // issue next iteration's loads (b+1; wraps to 0 on last iter, discarded)
        int bn = (b + 1 < NB) ? (b + 1) : 0;
        const short* hpn = hp0 + (size_t)(16 * bn) * 8;
        short8 nhr = *(const short8*)(hpn);
        short8 nhi = *(const short8*)(hpn + (size_t)HROWS * 8);
        short8 nnh = *(const short8*)(hpn + (size_t)(2 * HROWS) * 8);
        int lsn = xswz(ebase - 16 * bn);
        short8 nxr0 = *(const short8*)(&xr_s[0][lsn]);
        short8 nxi0 = *(const short8*)(&xi_s[0][lsn]);
        short8 nxr1 = *(const short8*)(&xr_s[1][lsn]);
        short8 nxi1 = *(const short8*)(&xi_s[1][lsn]);

        accr0 = MFMA32(fxr0, fhr, accr0);
        accr0 = MFMA32(fxi0, fnh, accr0);
        acci0 = MFMA32(fxr0, fhi, acci0);
        acci0 = MFMA32(fxi0, fhr, acci0);
        accr1 = MFMA32(fxr1, fhr, accr1);
        accr1 = MFMA32(fxi1, fnh, accr1);
        acci1 = MFMA32(fxr1, fhi, acci1);
        acci1 = MFMA32(fxi1, fhr, acci1);

        fhr = nhr; fhi = nhi; fnh = nnh;
        fxr0 = nxr0; fxi0 = nxi0; fxr1 = nxr1; fxi1 = nxi1;
    }

    // ---- epilogue: D col = lane&31, row = (reg&3) + 8*(reg>>2) + 4*half ----
    const int nw = N0 + wave * WAVE_OUT;
    #pragma unroll
    for (int p = 0; p < 2; ++p) {
        float2* __restrict__ op = out + (size_t)p * NOUT;
        const float16v& ar = p ? accr1 : accr0;
        const float16v& ai = p ? acci1 : acci0;
        #pragma unroll
        for (int v = 0; v < 16; ++v) {
            int row = (v & 3) + 8 * (v >> 2) + 4 * half;
            int n = nw + 32 * row + cc;
            if (n < NOUT) op[n] = make_float2(ar[v], ai[v]);
        }
    }
}

extern "C" void kernel_launch(void* const* d_in, const int* in_sizes, int n_in,
                              void* d_out, int out_size, void* d_ws, size_t ws_size,
                              hipStream_t stream) {
    const float* txr = (const float*)d_in[0];
    const float* txi = (const float*)d_in[1];
    const float* hr  = (const float*)d_in[2];
    const float* hi  = (const float*)d_in[3];
    float2* out = (float2*)d_out;
    short* hh = (short*)d_ws;   // 3 * 568 * 8 bf16 = 27 KB

    build_h<<<dim3((HROWS + BLK - 1) / BLK), BLK, 0, stream>>>(hr, hi, hh);

    fir_mfma32dp<<<dim3(NBLK), BLK, 0, stream>>>(txr, txi, hh, out);
}

// Round 5
// 140.423 us; speedup vs baseline: 3.5484x; 1.0433x over previous
//
#include <hip/hip_runtime.h>
#include <hip/hip_bf16.h>

// FixedChannelDP via Toeplitz-GEMM on bf16 MFMA 32x32x16.
// y[p,n] = sum_{k=0}^{512} h[k] x[p,n-k]  ('full' conv), out fp32 [2,NOUT,2].
//
// Block covers n in [N0, N0+2048) for BOTH pols; each wave owns one 32x32-tile
// strip of one pol (waves 0,1 -> pol 0; waves 2,3 -> pol 1) => acc = 32 regs.
//
// Mapping (b in [0,34)):
//   D[r][c] += sum_k A_b[r][k] * B_b[k][c],  n = nw + 32r + c
//   A_b[r][k] = x[nw + 32r + k + 16 - 16b]        (8 contiguous -> ds_read_b128)
//   B_b[k][c] = h[16b + c - k - 16]  (0 if OOB)   -> tap covered exactly once
// h table (global ws): hh[tab][R][j] = h[R-24-j], tab: 0=hr, 1=hi;
//   row read at R = 16b + cc - 8*half + 8.  re-part uses (-xi)*hi via v_xor.

#define NSAMP 4194304
#define LTAPS 513
#define NOUT  (NSAMP + LTAPS - 1)   // 4194816

#define BLK       256
#define WAVE_OUT  1024                  // one 32x32 D tile strip per wave
#define BLOCK_OUT 2048                  // per pol
#define HALO      512
#define XELEMS    (BLOCK_OUT + HALO + 16)   // 2576
#define NB        34
#define HROWS     568
#define NBLK      ((NOUT + BLOCK_OUT - 1) / BLOCK_OUT)  // 2049

typedef __attribute__((ext_vector_type(8)))  short short8;
typedef __attribute__((ext_vector_type(4)))  short short4v;
typedef __attribute__((ext_vector_type(4)))  int   int4v;
typedef __attribute__((ext_vector_type(16))) float float16v;

// x LDS swizzle: +8 elements (16 B) per 32 -> A-frag b128 reads hit all 32 banks.
__device__ __forceinline__ int xswz(int e) { return e + ((e >> 5) << 3); }
#define XSZ 3224   // xswz(2572)+4 = 3216, rounded up (8-short aligned)

__device__ __forceinline__ short f2b(float f) {
    __bf16 b = (__bf16)f;
    return __builtin_bit_cast(short, b);
}

__global__ __launch_bounds__(BLK)
void build_h(const float* __restrict__ hr, const float* __restrict__ hi,
             short* __restrict__ hh) {
    int R = blockIdx.x * BLK + threadIdx.x;
    if (R < HROWS) {
        short8 vr, vi;
        #pragma unroll
        for (int j = 0; j < 8; ++j) {
            int idx = R - 24 - j;
            bool ok = (idx >= 0) && (idx < LTAPS);
            vr[j] = f2b(ok ? hr[idx] : 0.0f);
            vi[j] = f2b(ok ? hi[idx] : 0.0f);
        }
        *(short8*)(hh + (size_t)(0 * HROWS + R) * 8) = vr;
        *(short8*)(hh + (size_t)(1 * HROWS + R) * 8) = vi;
    }
}

#define MFMA32(A, B, C) __builtin_amdgcn_mfma_f32_32x32x16_bf16((A), (B), (C), 0, 0, 0)

__device__ __forceinline__ short8 bneg8(short8 v) {
    int4v t = __builtin_bit_cast(int4v, v);
    t ^= (int4v){(int)0x80008000, (int)0x80008000, (int)0x80008000, (int)0x80008000};
    return __builtin_bit_cast(short8, t);
}

__global__ __launch_bounds__(BLK, 5)
void fir_mfma32w(const float* __restrict__ txr_all, const float* __restrict__ txi_all,
                 const short* __restrict__ hh, float2* __restrict__ out) {
    const int N0  = blockIdx.x * BLOCK_OUT;
    const int tid = threadIdx.x;

    __shared__ __align__(16) short xr_s[2][XSZ];
    __shared__ __align__(16) short xi_s[2][XSZ];

    // ---- stage x tiles (both pols) [N0-HALO, N0+BLOCK_OUT+16) as bf16, swizzled ----
    #pragma unroll
    for (int p = 0; p < 2; ++p) {
        const float* __restrict__ xr_g = txr_all + (size_t)p * NSAMP;
        const float* __restrict__ xi_g = txi_all + (size_t)p * NSAMP;
        #pragma unroll
        for (int it = 0; it < 3; ++it) {
            int e = (tid + it * BLK) * 4;
            if (e < XELEMS) {
                int g = N0 - HALO + e;
                float r0, r1, r2, r3, i0, i1, i2, i3;
                if (g >= 0 && g + 3 < NSAMP) {
                    float4 fr = *(const float4*)(xr_g + g);
                    float4 fi = *(const float4*)(xi_g + g);
                    r0 = fr.x; r1 = fr.y; r2 = fr.z; r3 = fr.w;
                    i0 = fi.x; i1 = fi.y; i2 = fi.z; i3 = fi.w;
                } else {
                    int gc0 = min(max(g + 0, 0), NSAMP - 1);
                    int gc1 = min(max(g + 1, 0), NSAMP - 1);
                    int gc2 = min(max(g + 2, 0), NSAMP - 1);
                    int gc3 = min(max(g + 3, 0), NSAMP - 1);
                    r0 = (g + 0 >= 0 && g + 0 < NSAMP) ? xr_g[gc0] : 0.0f;
                    r1 = (g + 1 >= 0 && g + 1 < NSAMP) ? xr_g[gc1] : 0.0f;
                    r2 = (g + 2 >= 0 && g + 2 < NSAMP) ? xr_g[gc2] : 0.0f;
                    r3 = (g + 3 >= 0 && g + 3 < NSAMP) ? xr_g[gc3] : 0.0f;
                    i0 = (g + 0 >= 0 && g + 0 < NSAMP) ? xi_g[gc0] : 0.0f;
                    i1 = (g + 1 >= 0 && g + 1 < NSAMP) ? xi_g[gc1] : 0.0f;
                    i2 = (g + 2 >= 0 && g + 2 < NSAMP) ? xi_g[gc2] : 0.0f;
                    i3 = (g + 3 >= 0 && g + 3 < NSAMP) ? xi_g[gc3] : 0.0f;
                }
                int ls = xswz(e);   // 4-aligned, never crosses a pad boundary
                short4v vr = { f2b(r0), f2b(r1), f2b(r2), f2b(r3) };
                short4v vi = { f2b(i0), f2b(i1), f2b(i2), f2b(i3) };
                *(short4v*)(&xr_s[p][ls]) = vr;
                *(short4v*)(&xi_s[p][ls]) = vi;
            }
        }
    }
    __syncthreads();

    // ---- MFMA main loop: one 32x32 tile strip per wave, one pol per wave ----
    const int lane = tid & 63;
    const int wave = tid >> 6;
    const int pol  = wave >> 1;     // waves 0,1 -> pol 0; 2,3 -> pol 1
    const int strip = wave & 1;     // n-offset strip within block
    const int cc   = lane & 31;     // A row r / B col c / D col
    const int half = lane >> 5;

    float16v acc_re = {0.f,0.f,0.f,0.f,0.f,0.f,0.f,0.f,0.f,0.f,0.f,0.f,0.f,0.f,0.f,0.f};
    float16v acc_im = acc_re;

    const int    ebase = HALO + strip * WAVE_OUT + 32 * cc + 8 * half + 16;
    const short* hp0   = hh + (size_t)(cc - 8 * half + 8) * 8;
    const short* xrp   = xr_s[pol];
    const short* xip   = xi_s[pol];

    for (int b = 0; b < NB; ++b) {
        const short* hp = hp0 + (size_t)(16 * b) * 8;
        short8 fhr = *(const short8*)(hp);
        short8 fhi = *(const short8*)(hp + (size_t)HROWS * 8);
        int ls = xswz(ebase - 16 * b);
        short8 fxr = *(const short8*)(xrp + ls);
        short8 fxi = *(const short8*)(xip + ls);
        short8 fnxi = bneg8(fxi);
        acc_re = MFMA32(fxr,  fhr, acc_re);
        acc_re = MFMA32(fnxi, fhi, acc_re);
        acc_im = MFMA32(fxi,  fhr, acc_im);
        acc_im = MFMA32(fxr,  fhi, acc_im);
    }

    // ---- epilogue: D col = lane&31, row = (reg&3) + 8*(reg>>2) + 4*half ----
    float2* __restrict__ op = out + (size_t)pol * NOUT;
    const int nw = N0 + strip * WAVE_OUT;
    #pragma unroll
    for (int v = 0; v < 16; ++v) {
        int row = (v & 3) + 8 * (v >> 2) + 4 * half;
        int n = nw + 32 * row + cc;
        if (n < NOUT) op[n] = make_float2(acc_re[v], acc_im[v]);
    }
}

extern "C" void kernel_launch(void* const* d_in, const int* in_sizes, int n_in,
                              void* d_out, int out_size, void* d_ws, size_t ws_size,
                              hipStream_t stream) {
    const float* txr = (const float*)d_in[0];
    const float* txi = (const float*)d_in[1];
    const float* hr  = (const float*)d_in[2];
    const float* hi  = (const float*)d_in[3];
    float2* out = (float2*)d_out;
    short* hh = (short*)d_ws;   // 2 * 568 * 8 bf16 = 18 KB

    build_h<<<dim3((HROWS + BLK - 1) / BLK), BLK, 0, stream>>>(hr, hi, hh);

    fir_mfma32w<<<dim3(NBLK), BLK, 0, stream>>>(txr, txi, hh, out);
}